// Round 6
// baseline (88.809 us; speedup 1.0000x reference)
//
#include <hip/hip_runtime.h>
#include <stdint.h>

#define H_ 224
#define W_ 224
#define NPIX (H_ * W_)          // 50176
#define NFRAMES 256
#define NQ4 (NPIX / 4)          // 12544 dwords per frame
#define ROWQ (W_ / 4)           // 56 dwords per row
#define GRAY_BYTES ((size_t)NFRAMES * NPIX)   // 12,845,056

__device__ __forceinline__ uint32_t udot4acc(uint32_t a, uint32_t b, uint32_t c) {
#if __has_builtin(__builtin_amdgcn_udot4)
    return __builtin_amdgcn_udot4(a, b, c, false);
#else
    c += (a & 0xffu) * (b & 0xffu);
    c += ((a >> 8) & 0xffu) * ((b >> 8) & 0xffu);
    c += ((a >> 16) & 0xffu) * ((b >> 16) & 0xffu);
    c += (a >> 24) * (b >> 24);
    return c;
#endif
}

__device__ __forceinline__ uint32_t quant1(float s) {
    float gr = s / 3.0f;
    float v = floorf(gr * 255.0f);
    v = fminf(fmaxf(v, 0.0f), 255.0f);
    return (uint32_t)(int)v;
}

// ---------------- Kernel 1: per-frame gray quantization + std sums ----------------
__global__ __launch_bounds__(1024, 4) void k_gray(const float* __restrict__ x,
                                                  uint32_t* __restrict__ g,
                                                  double* __restrict__ s12) {
    __shared__ uint32_t red1[16], red2[16];
    const int f = blockIdx.x;
    const int b = f >> 3, fr = f & 7;
    const int tid = threadIdx.x, lane = tid & 63, wave = tid >> 6;

    const float4* xc0 = reinterpret_cast<const float4*>(x + ((size_t)(b * 3 + 0) * 8 + fr) * NPIX);
    const float4* xc1 = reinterpret_cast<const float4*>(x + ((size_t)(b * 3 + 1) * 8 + fr) * NPIX);
    const float4* xc2 = reinterpret_cast<const float4*>(x + ((size_t)(b * 3 + 2) * 8 + fr) * NPIX);
    uint32_t* gf = g + (size_t)f * NQ4;

    uint32_t s1 = 0, s2 = 0;
    for (int i = tid; i < NQ4; i += 1024) {
        float4 a = xc0[i], bb = xc1[i], c = xc2[i];
        uint32_t v0 = quant1(a.x + bb.x + c.x);
        uint32_t v1 = quant1(a.y + bb.y + c.y);
        uint32_t v2 = quant1(a.z + bb.z + c.z);
        uint32_t v3 = quant1(a.w + bb.w + c.w);
        gf[i] = v0 | (v1 << 8) | (v2 << 16) | (v3 << 24);
        s1 += v0 + v1 + v2 + v3;
        s2 += v0 * v0 + v1 * v1 + v2 * v2 + v3 * v3;   // block total <= 3.27e9 < 2^32
    }
    #pragma unroll
    for (int off = 32; off; off >>= 1) {
        s1 += __shfl_down(s1, off, 64);
        s2 += __shfl_down(s2, off, 64);
    }
    if (lane == 0) { red1[wave] = s1; red2[wave] = s2; }
    __syncthreads();
    if (tid == 0) {
        uint32_t a1 = 0, a2 = 0;
        #pragma unroll
        for (int w = 0; w < 16; ++w) { a1 += red1[w]; a2 += red2[w]; }
        s12[f * 2 + 0] = (double)a1;
        s12[f * 2 + 1] = (double)a2;
    }
}

// ---------------- pair pass: global gray -> swizzled u8 histogram atomics ----------------
// Wave handles row r; lanes 0..55 read one dword (4 px) of row r and r+DR.
// Swizzle: word = ((a<<6)|(b>>2)) ^ (a&31) -> a mod 32 is near-uniform, spreads
// the concentrated b>>2 distribution across ALL 5 bank bits.
template<int DR, int DC>
__device__ __forceinline__ void pair_pass(const uint32_t* __restrict__ gf,
                                          uint32_t* hist, int wave, int lane) {
    constexpr int nr = H_ - DR;
    if (lane < 56) {
        for (int r = wave; r < nr; r += 8) {
            uint32_t A = gf[r * ROWQ + lane];
            uint32_t B = DR ? gf[(r + DR) * ROWQ + lane] : A;
            uint32_t Bv;
            if (DC == 1) {
                uint32_t Bn = __shfl_down(B, 1, 64);
                Bv = (B >> 8) | (Bn << 24);          // bytes = cols 4l+1 .. 4l+4
            } else if (DC == -1) {
                uint32_t Bp = __shfl_up(B, 1, 64);
                Bv = (B << 8) | (Bp >> 24);          // bytes = cols 4l-1 .. 4l+2
            } else {
                Bv = B;
            }
            int cb = lane * 4;
            #pragma unroll
            for (int k = 0; k < 4; ++k) {
                bool valid = (DC == 1) ? (cb + k < W_ - 1)
                           : (DC == -1) ? (cb + k >= 1)
                           : true;
                if (valid) {
                    uint32_t a = (A  >> (8 * k)) & 0xffu;
                    uint32_t b = (Bv >> (8 * k)) & 0xffu;
                    uint32_t w = ((a << 6) | (b >> 2)) ^ (a & 31u);
                    atomicAdd(&hist[w], 1u << ((b & 3u) << 3));
                }
            }
        }
    }
}

// ---- stats: con/dis/hom + sum(h^2) + cross sum(h_ij*h_ji), swizzle-decoded ----
__device__ __forceinline__ void stats_pass(const uint32_t* hist, int tid, int wave, int lane,
                                           double invnp, double inv2np2,
                                           double& conD, double& disD,
                                           double& homD, double& asmD) {
    uint32_t conU = 0, disU = 0, slinU = 0;
    float homF = 0.0f;
    #pragma unroll 4
    for (int itr = 0; itr < 32; ++itr) {
        int m = tid + (itr << 9);              // wave covers one row per iter
        uint32_t w = hist[m];
        if (w) {                               // empty rows skip wave-uniformly
            int i = m >> 6;
            int b4 = (m & 63) ^ (i & 31);      // undo swizzle
            int d0 = i - (b4 << 2);
            slinU = udot4acc(w, w, slinU);
            #pragma unroll
            for (int k = 0; k < 4; ++k) {
                uint32_t bv = (w >> (k << 3)) & 0xffu;
                int d = d0 - k;
                uint32_t d2 = (uint32_t)(d * d);
                conU += bv * d2;
                disU += bv * (uint32_t)(d < 0 ? -d : d);
                homF += (float)bv * __builtin_amdgcn_rcpf(1.0f + (float)d2);
            }
        }
    }

    // cross term over 4x4 byte tiles; unit (it=lane, jt=(lane+s)&63)
    uint32_t scrU = 0;
    #pragma unroll
    for (int q = 0; q < 8; ++q) {
        int s = wave + (q << 3);
        int jt = (lane + s) & 63;
        uint32_t A[4], Bw[4];
        #pragma unroll
        for (int k = 0; k < 4; ++k) {
            int ia = 4 * lane + k;
            A[k]  = hist[((ia << 6) | jt)   ^ (ia & 31)];
            int ib = 4 * jt + k;
            Bw[k] = hist[((ib << 6) | lane) ^ (ib & 31)];
        }
        if ((A[0] | A[1] | A[2] | A[3]) && (Bw[0] | Bw[1] | Bw[2] | Bw[3])) {
            uint32_t x0 = __builtin_amdgcn_perm(Bw[1], Bw[0], 0x05010400u);
            uint32_t x1 = __builtin_amdgcn_perm(Bw[1], Bw[0], 0x07030602u);
            uint32_t x2 = __builtin_amdgcn_perm(Bw[3], Bw[2], 0x05010400u);
            uint32_t x3 = __builtin_amdgcn_perm(Bw[3], Bw[2], 0x07030602u);
            uint32_t t0 = __builtin_amdgcn_perm(x2, x0, 0x05040100u);
            uint32_t t1 = __builtin_amdgcn_perm(x2, x0, 0x07060302u);
            uint32_t t2 = __builtin_amdgcn_perm(x3, x1, 0x05040100u);
            uint32_t t3 = __builtin_amdgcn_perm(x3, x1, 0x07060302u);
            scrU = udot4acc(A[0], t0, scrU);
            scrU = udot4acc(A[1], t1, scrU);
            scrU = udot4acc(A[2], t2, scrU);
            scrU = udot4acc(A[3], t3, scrU);
        }
    }

    conD += (double)conU * invnp;
    disD += (double)disU * invnp;
    homD += (double)homF * invnp;
    asmD += ((double)slinU + (double)scrU) * inv2np2;
}

// ---------------- Kernel 2: one (frame, offset) per block, 2 blocks/CU ----------------
__global__ __launch_bounds__(512, 4) void k_glcm(const uint32_t* __restrict__ g,
                                                 double* __restrict__ part) {
    __shared__ uint32_t hist[16384];   // 64 KB u8 H[256][256], swizzled words
    __shared__ double red[8 * 8];

    const int bid = blockIdx.x;
    const int o = bid >> 8;            // offset index (o-major: frame's 4 blocks
    const int f = bid & 255;           //  land on the same XCD mod 8)
    const uint32_t* gf = g + (size_t)f * NQ4;
    const int tid = threadIdx.x, lane = tid & 63, wave = tid >> 6;

    // zero histogram: 16384 words = 4096 uint4 / 512 threads = 8 each
    uint4* h4 = reinterpret_cast<uint4*>(hist);
    const uint4 z4 = make_uint4(0u, 0u, 0u, 0u);
    #pragma unroll
    for (int i = 0; i < 8; ++i) h4[tid + (i << 9)] = z4;
    __syncthreads();

    if (o == 0)      pair_pass<0,  1>(gf, hist, wave, lane);
    else if (o == 1) pair_pass<1,  1>(gf, hist, wave, lane);
    else if (o == 2) pair_pass<1,  0>(gf, hist, wave, lane);
    else             pair_pass<1, -1>(gf, hist, wave, lane);
    __syncthreads();

    double conD = 0.0, disD = 0.0, homD = 0.0, asmD = 0.0;
    const double np = (o & 1) ? 49729.0 : 49952.0;
    stats_pass(hist, tid, wave, lane, 1.0 / np, 1.0 / (2.0 * np * np),
               conD, disD, homD, asmD);

    // block reduction of 4 doubles
    double vals[4] = {conD, disD, homD, asmD};
    #pragma unroll
    for (int off = 32; off; off >>= 1) {
        #pragma unroll
        for (int i = 0; i < 4; ++i) vals[i] += __shfl_down(vals[i], off, 64);
    }
    if (lane == 0) {
        #pragma unroll
        for (int i = 0; i < 4; ++i) red[wave * 8 + i] = vals[i];
    }
    __syncthreads();
    if (tid == 0) {
        #pragma unroll
        for (int i = 0; i < 4; ++i) {
            double t = red[i];
            for (int w = 1; w < 8; ++w) t += red[w * 8 + i];
            part[(size_t)bid * 4 + i] = t;
        }
    }
}

// ---------------- Kernel 3: combine offsets, finalize ----------------
__global__ __launch_bounds__(256) void k_final(const double* __restrict__ s12,
                                               const double* __restrict__ part,
                                               float* __restrict__ out) {
    int f = threadIdx.x;                  // 256 frames, 1 block
    double con = 0.0, dis = 0.0, hom = 0.0, as = 0.0;
    #pragma unroll
    for (int o = 0; o < 4; ++o) {
        const double* p = part + (size_t)((o << 8) + f) * 4;
        con += p[0]; dis += p[1]; hom += p[2]; as += p[3];
    }
    con *= 0.25; dis *= 0.25; hom *= 0.25; as *= 0.25;
    double N = (double)NPIX;
    double mean = s12[f * 2] / N;
    double var = s12[f * 2 + 1] / N - mean * mean;
    if (var < 0.0) var = 0.0;
    float* op = out + f * 6;
    op[0] = (float)sqrt(var);
    op[1] = (float)con;
    op[2] = (float)dis;
    op[3] = (float)hom;
    op[4] = (float)as;
    op[5] = (float)sqrt(as);
}

extern "C" void kernel_launch(void* const* d_in, const int* in_sizes, int n_in,
                              void* d_out, int out_size, void* d_ws, size_t ws_size,
                              hipStream_t stream) {
    const float* x = (const float*)d_in[0];
    float* out = (float*)d_out;
    uint32_t* g = (uint32_t*)d_ws;                                        // 12.8 MB
    double* s12  = (double*)((uint8_t*)d_ws + GRAY_BYTES);                // 256*2 doubles
    double* part = (double*)((uint8_t*)d_ws + GRAY_BYTES + NFRAMES * 16); // 1024*4 doubles

    k_gray<<<NFRAMES, 1024, 0, stream>>>(x, g, s12);
    k_glcm<<<NFRAMES * 4, 512, 0, stream>>>(g, part);
    k_final<<<1, 256, 0, stream>>>(s12, part, out);
}

// Round 7
// 78.458 us; speedup vs baseline: 1.1319x; 1.1319x over previous
//
#include <hip/hip_runtime.h>
#include <stdint.h>

#define H_ 224
#define W_ 224
#define NPIX (H_ * W_)          // 50176
#define NQ4 (NPIX / 4)          // 12544 dwords per frame
#define NFRAMES 256
#define NT 1024
#define NW 16
#define CROWS 8
#define NCHUNK (H_ / CROWS)     // 28
#define CPX (CROWS * W_)        // 1792 px per chunk
#define CQ4 (CPX / 4)           // 448 dwords per chunk
#define STG (3 * CPX)           // 5376 f32 per staging buffer

typedef __attribute__((address_space(1))) const uint32_t* gas_t;
typedef __attribute__((address_space(3))) uint32_t* las_t;

__device__ __forceinline__ void gload_lds16(const float* g, float* l) {
    __builtin_amdgcn_global_load_lds((gas_t)g, (las_t)l, 16, 0, 0);
}

__device__ __forceinline__ uint32_t udot4acc(uint32_t a, uint32_t b, uint32_t c) {
#if __has_builtin(__builtin_amdgcn_udot4)
    return __builtin_amdgcn_udot4(a, b, c, false);
#else
    c += (a & 0xffu) * (b & 0xffu);
    c += ((a >> 8) & 0xffu) * ((b >> 8) & 0xffu);
    c += ((a >> 16) & 0xffu) * ((b >> 16) & 0xffu);
    c += (a >> 24) * (b >> 24);
    return c;
#endif
}

__device__ __forceinline__ uint32_t quant1(float s) {
    float gr = s / 3.0f;
    float v = floorf(gr * 255.0f);
    v = fminf(fmaxf(v, 0.0f), 255.0f);
    return (uint32_t)(int)v;
}

// swizzled histogram word index: bank = ((b>>2) ^ (a&31)) & 31 is near-uniform
__device__ __forceinline__ void hist_inc(uint32_t* hist, uint32_t a, uint32_t b) {
    uint32_t w = ((a << 6) | (b >> 2)) ^ (a & 31u);
    atomicAdd(&hist[w], 1u << ((b & 3u) << 3));
}

// ---- pair pass for (1,*) offsets from LDS gray ----
template<int DR, int DC>
__device__ __forceinline__ void pair_pass(const uint32_t* gsh, uint32_t* hist,
                                          int wave, int lane) {
    constexpr int nr = H_ - DR;
    if (lane < 56) {
        for (int r = wave; r < nr; r += NW) {
            uint32_t A = gsh[r * 56 + lane];
            uint32_t B = gsh[(r + DR) * 56 + lane];
            uint32_t Bv;
            if (DC == 1) {
                uint32_t Bn = __shfl_down(B, 1, 64);
                Bv = (B >> 8) | (Bn << 24);
            } else if (DC == -1) {
                uint32_t Bp = __shfl_up(B, 1, 64);
                Bv = (B << 8) | (Bp >> 24);
            } else {
                Bv = B;
            }
            int cb = lane * 4;
            #pragma unroll
            for (int k = 0; k < 4; ++k) {
                bool valid = (DC == 1) ? (cb + k < W_ - 1)
                           : (DC == -1) ? (cb + k >= 1)
                           : true;
                if (valid) {
                    uint32_t a = (A  >> (8 * k)) & 0xffu;
                    uint32_t b = (Bv >> (8 * k)) & 0xffu;
                    hist_inc(hist, a, b);
                }
            }
        }
    }
}

// ---- stats: con/dis/hom + sum(h^2) + cross sum(h_ij*h_ji), swizzle-decoded ----
__device__ __forceinline__ void stats_pass(const uint32_t* hist, int tid, int wave, int lane,
                                           double invnp, double inv2np2,
                                           double& conD, double& disD,
                                           double& homD, double& asmD) {
    uint32_t conU = 0, disU = 0, slinU = 0;
    float homF = 0.0f;
    #pragma unroll 4
    for (int itr = 0; itr < 16; ++itr) {
        int m = tid + (itr << 10);
        uint32_t w = hist[m];
        if (w) {                                   // empty rows skip (execz)
            int i = m >> 6;
            int b4 = (m & 63) ^ (i & 31);          // undo swizzle
            int d0 = i - (b4 << 2);
            slinU = udot4acc(w, w, slinU);
            #pragma unroll
            for (int k = 0; k < 4; ++k) {
                uint32_t bv = (w >> (k << 3)) & 0xffu;
                int d = d0 - k;
                uint32_t d2 = (uint32_t)(d * d);
                conU += bv * d2;
                disU += bv * (uint32_t)(d < 0 ? -d : d);
                homF += (float)bv * __builtin_amdgcn_rcpf(1.0f + (float)d2);
            }
        }
    }

    // cross term over 4x4 byte tiles; unit (it=lane, jt=(lane+s)&63)
    uint32_t scrU = 0;
    #pragma unroll
    for (int q = 0; q < 4; ++q) {
        int s = wave + (q << 4);
        int jt = (lane + s) & 63;
        uint32_t A[4], Bw[4];
        #pragma unroll
        for (int k = 0; k < 4; ++k) {
            int ia = 4 * lane + k;
            A[k]  = hist[((ia << 6) | jt)   ^ (ia & 31)];
            int ib = 4 * jt + k;
            Bw[k] = hist[((ib << 6) | lane) ^ (ib & 31)];
        }
        if ((A[0] | A[1] | A[2] | A[3]) && (Bw[0] | Bw[1] | Bw[2] | Bw[3])) {
            uint32_t x0 = __builtin_amdgcn_perm(Bw[1], Bw[0], 0x05010400u);
            uint32_t x1 = __builtin_amdgcn_perm(Bw[1], Bw[0], 0x07030602u);
            uint32_t x2 = __builtin_amdgcn_perm(Bw[3], Bw[2], 0x05010400u);
            uint32_t x3 = __builtin_amdgcn_perm(Bw[3], Bw[2], 0x07030602u);
            uint32_t t0 = __builtin_amdgcn_perm(x2, x0, 0x05040100u);
            uint32_t t1 = __builtin_amdgcn_perm(x2, x0, 0x07060302u);
            uint32_t t2 = __builtin_amdgcn_perm(x3, x1, 0x05040100u);
            uint32_t t3 = __builtin_amdgcn_perm(x3, x1, 0x07060302u);
            scrU = udot4acc(A[0], t0, scrU);
            scrU = udot4acc(A[1], t1, scrU);
            scrU = udot4acc(A[2], t2, scrU);
            scrU = udot4acc(A[3], t3, scrU);
        }
    }

    conD += (double)conU * invnp;
    disD += (double)disU * invnp;
    homD += (double)homF * invnp;
    asmD += ((double)slinU + (double)scrU) * inv2np2;
}

// ---------------- fused kernel: one frame per block ----------------
__global__ __launch_bounds__(NT, 4) void k_fused(const float* __restrict__ x,
                                                 float* __restrict__ out) {
    __shared__ float stage[2][STG];    // 43008 B: DMA staging, double-buffered
    __shared__ uint32_t hist[16384];   // 65536 B: u8 H[256][256], swizzled words
    __shared__ uint32_t gsh[NQ4];      // 50176 B: gray frame, 4 px/word
    __shared__ double red[NW * 8];     // 1024 B

    const int f = blockIdx.x;
    const int bq = f >> 3, fq = f & 7;
    const int tid = threadIdx.x, lane = tid & 63, wave = tid >> 6;

    // x base for this frame; channel stride = 8*NPIX floats
    const float* xb = x + ((size_t)bq * 24 + fq) * NPIX;

    // zero hist (overlaps first DMA; completes at first barrier)
    uint4* h4 = reinterpret_cast<uint4*>(hist);
    const uint4 z4 = make_uint4(0u, 0u, 0u, 0u);
    #pragma unroll
    for (int i = 0; i < 4; ++i) h4[tid + (i << 10)] = z4;

    // DMA chunk 0 -> stage[0] (waves 9..15: 3 x 1KB instrs each, 21 total)
    if (wave >= 9) {
        int base = (wave - 9) * 3;
        #pragma unroll
        for (int k = 0; k < 3; ++k) {
            int idx = base + k;
            int ch = idx / 7, blk = idx % 7;
            gload_lds16(xb + (size_t)ch * (8 * NPIX) + blk * 256 + lane * 4,
                        &stage[0][ch * CPX + blk * 256]);
        }
    }
    __syncthreads();   // drains vmcnt(0): chunk 0 staged, hist zeroed

    // ---- streaming phase: DMA(c+1) || quant(c)+gray+std+(0,1) atomics ----
    uint32_t s1 = 0, s2 = 0;
    for (int c = 0; c < NCHUNK; ++c) {
        const int bs = c & 1;
        if (c + 1 < NCHUNK && wave >= 9) {
            int base = (wave - 9) * 3;
            #pragma unroll
            for (int k = 0; k < 3; ++k) {
                int idx = base + k;
                int ch = idx / 7, blk = idx % 7;
                gload_lds16(xb + (size_t)ch * (8 * NPIX) + (size_t)(c + 1) * CPX + blk * 256 + lane * 4,
                            &stage[bs ^ 1][ch * CPX + blk * 256]);
            }
        }
        if (tid < CQ4) {                     // waves 0..6 process chunk c
            const float* st = stage[bs];
            float4 av = *reinterpret_cast<const float4*>(st + 0 * CPX + 4 * tid);
            float4 bv = *reinterpret_cast<const float4*>(st + 1 * CPX + 4 * tid);
            float4 cv = *reinterpret_cast<const float4*>(st + 2 * CPX + 4 * tid);
            uint32_t v0 = quant1(av.x + bv.x + cv.x);
            uint32_t v1 = quant1(av.y + bv.y + cv.y);
            uint32_t v2 = quant1(av.z + bv.z + cv.z);
            uint32_t v3 = quant1(av.w + bv.w + cv.w);
            uint32_t pk = v0 | (v1 << 8) | (v2 << 16) | (v3 << 24);
            gsh[c * CQ4 + tid] = pk;
            s1 += v0 + v1 + v2 + v3;
            s2 += v0 * v0 + v1 * v1 + v2 * v2 + v3 * v3;
            // offset (0,1) pairs, fused into the stream
            uint32_t nx = __shfl_down(pk, 1, 64);
            #pragma unroll
            for (int k = 0; k < 3; ++k) {    // in-dword pairs: always valid
                uint32_t a = (pk >> (8 * k)) & 0xffu;
                uint32_t b = (pk >> (8 * k + 8)) & 0xffu;
                hist_inc(hist, a, b);
            }
            int m56 = tid % 56;              // c*448 == 0 mod 56
            if (lane != 63 && m56 != 55) {   // cross-dword pair
                hist_inc(hist, pk >> 24, nx & 0xffu);
            }
        }
        __syncthreads();   // drains DMA(c+1); gsh chunk c visible
    }

    // deferred lane-63 cross-dword pairs for (0,1): i = 64m+63
    if (tid < 196) {
        int i = tid * 64 + 63;
        if (i % 56 != 55) {
            hist_inc(hist, gsh[i] >> 24, gsh[i + 1] & 0xffu);
        }
    }
    __syncthreads();

    double conD = 0.0, disD = 0.0, homD = 0.0, asmD = 0.0;
    const double npA = 49952.0, npB = 49729.0;
    const double invA = 1.0 / npA, invB = 1.0 / npB;
    const double invA2 = 1.0 / (2.0 * npA * npA), invB2 = 1.0 / (2.0 * npB * npB);

    stats_pass(hist, tid, wave, lane, invA, invA2, conD, disD, homD, asmD);
    __syncthreads();

    // ---- offset (1,1) ----
    #pragma unroll
    for (int i = 0; i < 4; ++i) h4[tid + (i << 10)] = z4;
    __syncthreads();
    pair_pass<1, 1>(gsh, hist, wave, lane);
    __syncthreads();
    stats_pass(hist, tid, wave, lane, invB, invB2, conD, disD, homD, asmD);
    __syncthreads();

    // ---- offset (1,0) ----
    #pragma unroll
    for (int i = 0; i < 4; ++i) h4[tid + (i << 10)] = z4;
    __syncthreads();
    pair_pass<1, 0>(gsh, hist, wave, lane);
    __syncthreads();
    stats_pass(hist, tid, wave, lane, invA, invA2, conD, disD, homD, asmD);
    __syncthreads();

    // ---- offset (1,-1) ----
    #pragma unroll
    for (int i = 0; i < 4; ++i) h4[tid + (i << 10)] = z4;
    __syncthreads();
    pair_pass<1, -1>(gsh, hist, wave, lane);
    __syncthreads();
    stats_pass(hist, tid, wave, lane, invB, invB2, conD, disD, homD, asmD);
    __syncthreads();

    // ---- fused reduction of 6 doubles, finalize ----
    double vals[6] = {(double)s1, (double)s2, conD, disD, homD, asmD};
    #pragma unroll
    for (int off = 32; off; off >>= 1) {
        #pragma unroll
        for (int i = 0; i < 6; ++i) vals[i] += __shfl_down(vals[i], off, 64);
    }
    if (lane == 0) {
        #pragma unroll
        for (int i = 0; i < 6; ++i) red[wave * 8 + i] = vals[i];
    }
    __syncthreads();
    if (tid == 0) {
        double acc[6];
        #pragma unroll
        for (int i = 0; i < 6; ++i) {
            double t = red[i];
            for (int w = 1; w < NW; ++w) t += red[w * 8 + i];
            acc[i] = t;
        }
        double N = (double)NPIX;
        double mean = acc[0] / N;
        double var = acc[1] / N - mean * mean;
        if (var < 0.0) var = 0.0;
        float* op = out + f * 6;
        op[0] = (float)sqrt(var);
        op[1] = (float)(acc[2] * 0.25);
        op[2] = (float)(acc[3] * 0.25);
        op[3] = (float)(acc[4] * 0.25);
        op[4] = (float)(acc[5] * 0.25);
        op[5] = (float)sqrt(acc[5] * 0.25);
    }
}

extern "C" void kernel_launch(void* const* d_in, const int* in_sizes, int n_in,
                              void* d_out, int out_size, void* d_ws, size_t ws_size,
                              hipStream_t stream) {
    const float* x = (const float*)d_in[0];
    float* out = (float*)d_out;
    k_fused<<<NFRAMES, NT, 0, stream>>>(x, out);
}